// Round 2
// baseline (605.349 us; speedup 1.0000x reference)
//
#include <hip/hip_runtime.h>
#include <hip/hip_bf16.h>

typedef __attribute__((ext_vector_type(8))) short short8;
typedef __attribute__((ext_vector_type(4))) float floatx4;
typedef unsigned short u16;
typedef unsigned int u32;

#define BATCH 16
#define HH 224
#define WW 224
#define ICN 64
#define OCN 128
#define HP 226
#define WP 226

// conv tile geometry: M=80 pixels per WG (3 chunks/row, w0 = 0,72,144; 16-col overlap benign)
#define MT 80
#define AROWS_USED 246        // 3 * 82 rows of 64 ic (128 B each)
#define A_BYTES (248*128)     // 31744 (2 pad rows, unused)
#define BT_BYTES 16384        // 128 oc x 64 ic x 2B
#define LDS_BYTES (A_BYTES + 2*BT_BYTES)   // 64512 <= 64 KiB static

// ---- runtime dtype detection: bf16 halves have sane exponent fields; fp32 low
// halves are uniform mantissa bits. Deterministic, same every call (graph-safe).
__device__ __forceinline__ bool detect_bf16(const u32* __restrict__ xw) {
  int cnt = 0;
  #pragma unroll 8
  for (int i = 0; i < 64; ++i) {
    u32 w = xw[i];
    int e0 = (w >> 7) & 0xFF;    // low  u16 exponent field (bf16 view)
    int e1 = (w >> 23) & 0xFF;   // high u16 exponent field
    cnt += (e0 >= 90 && e0 <= 160) ? 1 : 0;
    cnt += (e1 >= 90 && e1 <= 160) ? 1 : 0;
  }
  return cnt >= 120;             // bf16 ~128, fp32 ~82
}

__device__ __forceinline__ u16 f2bf(float f) {
  __hip_bfloat16 h = __float2bfloat16(f);
  return *reinterpret_cast<u16*>(&h);
}

__device__ __forceinline__ float fast_tanh(float x) {
  float e = __expf(2.0f * x);    // x>>0 -> 1, x<<0 -> -1, inf-safe
  return 1.0f - 2.0f / (e + 1.0f);
}

// ---------- prep_x: NCHW (bf16 or fp32) -> zero-padded NHWC bf16 [b][226][226][64] ----------
__global__ __launch_bounds__(256) void prep_x(const void* __restrict__ xv, u16* __restrict__ xb) {
  __shared__ u16 tile[64*65];    // [wl][ic], stride 65 breaks bank conflicts
  const int tid = threadIdx.x;
  int bid = blockIdx.x;
  const int chunk = bid & 3;     // 4 chunks of 64 input cols
  int rest = bid >> 2;
  const int hp = rest % HP;
  const int b = rest / HP;
  const int wt = chunk * 64;
  const int h = hp - 1;
  const bool rowvalid = (h >= 0) && (h < HH);
  const bool isbf = detect_bf16((const u32*)xv);

  #pragma unroll
  for (int p = 0; p < 2; ++p) {  // 512 jobs: 64 ic x 8 octs of 8 w
    int idx = p*256 + tid;
    int ic = idx >> 3;
    int oct = idx & 7;
    int w = wt + oct*8;
    bool valid = rowvalid && (w < WW);
    size_t base = (((size_t)(b*ICN + ic))*HH + h)*WW + w;  // only deref'd if valid
    u16 vals[8];
    if (isbf) {
      short8 v = {0,0,0,0,0,0,0,0};
      if (valid) v = *(const short8*)((const u16*)xv + base);
      #pragma unroll
      for (int s = 0; s < 8; ++s) vals[s] = (u16)v[s];
    } else {
      floatx4 f0 = {0.f,0.f,0.f,0.f}, f1 = {0.f,0.f,0.f,0.f};
      if (valid) {
        f0 = *(const floatx4*)((const float*)xv + base);
        f1 = *(const floatx4*)((const float*)xv + base + 4);
      }
      #pragma unroll
      for (int s = 0; s < 4; ++s) { vals[s] = f2bf(f0[s]); vals[4+s] = f2bf(f1[s]); }
    }
    #pragma unroll
    for (int s = 0; s < 8; ++s)
      tile[(oct*8 + s)*65 + ic] = vals[s];
  }
  __syncthreads();
  #pragma unroll
  for (int p = 0; p < 2; ++p) {  // 512 jobs: 64 wl x 8 ic-chunks
    int idx = p*256 + tid;
    int wl = idx >> 3;
    int icc = idx & 7;
    int wp = wt + 1 + wl;        // padded col
    if (wp < WP) {
      short8 o;
      #pragma unroll
      for (int j = 0; j < 8; ++j) o[j] = (short)tile[wl*65 + icc*8 + j];
      *(short8*)(xb + (((size_t)(b*HP) + hp)*WP + wp)*ICN + icc*8) = o;
    }
  }
  if (chunk == 0 && tid < 8) {   // left border column wp=0
    short8 z = {0,0,0,0,0,0,0,0};
    *(short8*)(xb + (((size_t)(b*HP) + hp)*WP)*ICN + tid*8) = z;
  }
}

// ---------- prep_w: OIHW (bf16 or fp32) -> [oc][tap*64+ic] bf16 ----------
__global__ __launch_bounds__(256) void prep_w(const void* __restrict__ wv_, u16* __restrict__ wb,
                                              const u32* __restrict__ xdet) {
  const bool isbf = detect_bf16(xdet);
  int o = blockIdx.x*256 + threadIdx.x;   // 0..73727
  int oc = o / 576;
  int k = o - oc*576;
  int tap = k >> 6;
  int ic = k & 63;
  int src = oc*576 + ic*9 + tap;
  wb[o] = isbf ? ((const u16*)wv_)[src] : f2bf(((const float*)wv_)[src]);
}

// ---------- fused conv3x3 + bias + min_oc + double tanh ----------
__global__ __launch_bounds__(256, 2) void conv_min_kernel(
    const u16* __restrict__ xb, const u16* __restrict__ wb,
    const void* __restrict__ biasv, void* __restrict__ outv,
    const u32* __restrict__ xdet)
{
  __shared__ __align__(16) char smem[LDS_BYTES];
  char* ldsA = smem;                       // 248 rows x 128 B, XOR-swizzled 16B chunks
  char* ldsB = smem + A_BYTES;             // 2 x 16 KB
  float* minbuf = (float*)smem;            // aliased over A rows 0..10 (tap-8 reads rows >=166)

  const int tid = threadIdx.x;
  const int wv = tid >> 6;
  const int lane = tid & 63;
  const int m15 = lane & 15;
  const int quad = lane >> 4;
  const int cp = lane & 7;

  const bool isbf = detect_bf16(xdet);

  int bid = blockIdx.x;
  const int wsel = bid % 3;
  int rest = bid / 3;
  const int h = rest % HH;
  const int b = rest / HH;
  const int w0 = wsel * 72;                // 0,72,144

  // ---- stage A once: row r = dy*82 + wloc holds padded col w0+wloc of input row h+dy.
  // 16B chunk of logical ic-chunk c stored at slot c ^ (r&7).
  for (int q = tid; q < AROWS_USED*8; q += 256) {
    int r = q >> 3;
    int slot = q & 7;
    int c = slot ^ (r & 7);
    int dy = (r >= 164) ? 2 : ((r >= 82) ? 1 : 0);
    int wloc = r - dy*82;
    short8 v = *(const short8*)(xb + (((size_t)(b*HP + h + dy))*WP + (w0 + wloc))*ICN + c*8);
    *(short8*)(ldsA + r*128 + slot*16) = v;
  }

  // ---- B tap 0 into registers (4 x 16B per thread covers 128 oc x 64 ic)
  short8 breg[4];
  #pragma unroll
  for (int i = 0; i < 4; ++i) {
    int q = tid*4 + i;
    int oc = q >> 3;
    int c = (q & 7) ^ (oc & 7);
    breg[i] = *(const short8*)(wb + oc*576 + c*8);
  }

  floatx4 acc[5][2];
  #pragma unroll
  for (int mb = 0; mb < 5; ++mb) {
    acc[mb][0] = (floatx4){0.f,0.f,0.f,0.f};
    acc[mb][1] = (floatx4){0.f,0.f,0.f,0.f};
  }

  for (int tap = 0; tap < 9; ++tap) {
    char* bdst = ldsB + (tap & 1)*BT_BYTES;
    #pragma unroll
    for (int i = 0; i < 4; ++i) {          // write this tap's B to LDS
      int q = tid*4 + i;
      *(short8*)(bdst + (q >> 3)*128 + (q & 7)*16) = breg[i];
    }
    short8 bnext[4];
    if (tap < 8) {                         // prefetch next tap's B into registers
      #pragma unroll
      for (int i = 0; i < 4; ++i) {
        int q = tid*4 + i;
        int oc = q >> 3;
        int c = (q & 7) ^ (oc & 7);
        bnext[i] = *(const short8*)(wb + oc*576 + (tap+1)*64 + c*8);
      }
    }
    __syncthreads();                       // A+B visible; also fences buf[tap&1] reuse

    const int dy = tap / 3;
    const int dx = tap - dy*3;
    const int rbase = dy*82 + dx + m15;    // A row for this lane (+ mb*16)
    const char* ab = ldsA + rbase*128;
    const char* bb = bdst + (wv*32 + m15)*128;
    #pragma unroll
    for (int ks = 0; ks < 2; ++ks) {
      const int csel = ks*4 + quad;
      const int aoff = (csel ^ (rbase & 7)) * 16;
      const int boff = (csel ^ cp) * 16;   // row&7 == cp for B rows read here
      short8 af[5], bfr[2];
      #pragma unroll
      for (int mb = 0; mb < 5; ++mb)
        af[mb] = *(const short8*)(ab + mb*2048 + aoff);
      bfr[0] = *(const short8*)(bb + boff);
      bfr[1] = *(const short8*)(bb + 2048 + boff);
      #pragma unroll
      for (int mb = 0; mb < 5; ++mb) {
        acc[mb][0] = __builtin_amdgcn_mfma_f32_16x16x32_bf16(af[mb], bfr[0], acc[mb][0], 0, 0, 0);
        acc[mb][1] = __builtin_amdgcn_mfma_f32_16x16x32_bf16(af[mb], bfr[1], acc[mb][1], 0, 0, 0);
      }
    }
    if (tap < 8) {
      #pragma unroll
      for (int i = 0; i < 4; ++i) breg[i] = bnext[i];
    }
  }
  __syncthreads();   // fence LDS reads before minbuf aliasing writes (belt & braces)

  // ---- epilogue: +bias, min over oc, cross-lane/cross-wave min, tanh(tanh), store
  float bv0, bv1;
  if (isbf) {
    bv0 = __bfloat162float(((const __hip_bfloat16*)biasv)[wv*32 + m15]);
    bv1 = __bfloat162float(((const __hip_bfloat16*)biasv)[wv*32 + 16 + m15]);
  } else {
    bv0 = ((const float*)biasv)[wv*32 + m15];
    bv1 = ((const float*)biasv)[wv*32 + 16 + m15];
  }
  #pragma unroll
  for (int mb = 0; mb < 5; ++mb) {
    #pragma unroll
    for (int r = 0; r < 4; ++r) {
      float v = fminf(acc[mb][0][r] + bv0, acc[mb][1][r] + bv1);
      v = fminf(v, __shfl_xor(v, 1));
      v = fminf(v, __shfl_xor(v, 2));
      v = fminf(v, __shfl_xor(v, 4));
      v = fminf(v, __shfl_xor(v, 8));
      if (m15 == 0)
        minbuf[wv*MT + mb*16 + quad*4 + r] = v;   // pixel = mb*16 + quad*4 + r
    }
  }
  __syncthreads();
  if (tid < MT) {
    float v = fminf(fminf(minbuf[tid], minbuf[MT + tid]),
                    fminf(minbuf[2*MT + tid], minbuf[3*MT + tid]));
    float t = fast_tanh(fast_tanh(v));
    size_t oi = ((size_t)(b*HH + h))*WW + w0 + tid;
    if (isbf) ((__hip_bfloat16*)outv)[oi] = __float2bfloat16(t);
    else      ((float*)outv)[oi] = t;
  }
}

extern "C" void kernel_launch(void* const* d_in, const int* in_sizes, int n_in,
                              void* d_out, int out_size, void* d_ws, size_t ws_size,
                              hipStream_t stream) {
  (void)in_sizes; (void)n_in; (void)out_size;
  const size_t XB_BYTES = (size_t)BATCH*HP*WP*ICN*2;   // 104,603,648
  const size_t WB_BYTES = (size_t)OCN*ICN*9*2;         // 147,456
  if (ws_size < XB_BYTES + WB_BYTES) return;

  const void* x  = d_in[0];
  const void* w  = d_in[1];
  const void* bias = d_in[2];
  u16* xb = (u16*)d_ws;
  u16* wb = (u16*)((char*)d_ws + XB_BYTES);
  const u32* xdet = (const u32*)x;

  prep_x<<<BATCH*HP*4, 256, 0, stream>>>(x, xb);
  prep_w<<<288, 256, 0, stream>>>(w, wb, xdet);
  conv_min_kernel<<<3*HH*BATCH, 256, 0, stream>>>(xb, wb, bias, d_out, xdet);
}

// Round 3
// 496.888 us; speedup vs baseline: 1.2183x; 1.2183x over previous
//
#include <hip/hip_runtime.h>
#include <hip/hip_bf16.h>

typedef __attribute__((ext_vector_type(8))) short short8;
typedef __attribute__((ext_vector_type(4))) float floatx4;
typedef unsigned short u16;
typedef unsigned int u32;

#define BATCH 16
#define HH 224
#define WW 224
#define ICN 64
#define OCN 128
#define HP 226
#define WP 226

// conv tile geometry: M=80 pixels per WG (3 chunks/row, w0 = 0,72,144; 16-col overlap benign)
#define MT 80
#define AROWS_USED 246        // 3 * 82 rows of 64 ic (128 B each)
#define A_BYTES (248*128)     // 31744 (2 pad rows, unused)

// ---- runtime dtype detection (bench confirmed bf16; keep dual-path for safety)
__device__ __forceinline__ bool detect_bf16(const u32* __restrict__ xw) {
  int cnt = 0;
  #pragma unroll 8
  for (int i = 0; i < 64; ++i) {
    u32 w = xw[i];
    int e0 = (w >> 7) & 0xFF;
    int e1 = (w >> 23) & 0xFF;
    cnt += (e0 >= 90 && e0 <= 160) ? 1 : 0;
    cnt += (e1 >= 90 && e1 <= 160) ? 1 : 0;
  }
  return cnt >= 120;
}

__device__ __forceinline__ u16 f2bf(float f) {
  __hip_bfloat16 h = __float2bfloat16(f);
  return *reinterpret_cast<u16*>(&h);
}

__device__ __forceinline__ float fast_tanh(float x) {
  float e = __expf(2.0f * x);
  return 1.0f - 2.0f / (e + 1.0f);
}

// ---------- prep_x: NCHW (bf16/fp32) -> zero-padded NHWC bf16 [b][226][226][64] ----------
// u32-granular LDS transpose, conflict-free both phases.
__global__ __launch_bounds__(256) void prep_x(const void* __restrict__ xv, u16* __restrict__ xb) {
  __shared__ u32 tile32[64*33];  // [w_local][ic_pair], stride 33: bank = (w*8... + icp)%32, 2-way max
  const int tid = threadIdx.x;
  int bid = blockIdx.x;
  const int chunk = bid & 3;     // 4 chunks of 64 input cols
  int rest = bid >> 2;
  const int hp = rest % HP;
  const int b = rest / HP;
  const int wt = chunk * 64;
  const int h = hp - 1;
  const bool rowvalid = (h >= 0) && (h < HH);
  const bool isbf = detect_bf16((const u32*)xv);

  // phase 1: each thread reads 2 ic-rows x 8 w, writes 8 packed u32 (conflict-free)
  {
    const int icp = tid >> 3;    // ic pair 0..31
    const int oct = tid & 7;     // 8 w's
    const int w = wt + oct*8;
    const bool valid = rowvalid && (w < WW);
    const int ic0 = icp*2;
    u16 a[8], c[8];
    if (isbf) {
      short8 v0 = {0,0,0,0,0,0,0,0}, v1 = {0,0,0,0,0,0,0,0};
      if (valid) {
        v0 = *(const short8*)((const u16*)xv + (((size_t)(b*ICN + ic0))*HH + h)*WW + w);
        v1 = *(const short8*)((const u16*)xv + (((size_t)(b*ICN + ic0+1))*HH + h)*WW + w);
      }
      #pragma unroll
      for (int s = 0; s < 8; ++s) { a[s] = (u16)v0[s]; c[s] = (u16)v1[s]; }
    } else {
      floatx4 f0={0,0,0,0}, f1={0,0,0,0}, f2={0,0,0,0}, f3={0,0,0,0};
      if (valid) {
        const float* p0 = (const float*)xv + (((size_t)(b*ICN + ic0))*HH + h)*WW + w;
        const float* p1 = (const float*)xv + (((size_t)(b*ICN + ic0+1))*HH + h)*WW + w;
        f0 = *(const floatx4*)p0; f1 = *(const floatx4*)(p0+4);
        f2 = *(const floatx4*)p1; f3 = *(const floatx4*)(p1+4);
      }
      #pragma unroll
      for (int s = 0; s < 4; ++s) {
        a[s] = f2bf(f0[s]); a[4+s] = f2bf(f1[s]);
        c[s] = f2bf(f2[s]); c[4+s] = f2bf(f3[s]);
      }
    }
    #pragma unroll
    for (int s = 0; s < 8; ++s)
      tile32[(oct*8 + s)*33 + icp] = (u32)a[s] | ((u32)c[s] << 16);
  }
  __syncthreads();
  // phase 2: 512 jobs: 64 w_local x 8 ic-chunks; 4 u32 reads -> short8 global write
  #pragma unroll
  for (int p = 0; p < 2; ++p) {
    int idx = p*256 + tid;
    int wl = idx >> 3;
    int icc = idx & 7;
    int wp = wt + 1 + wl;
    if (wp < WP) {
      u32 cc[4];
      #pragma unroll
      for (int j = 0; j < 4; ++j) cc[j] = tile32[wl*33 + icc*4 + j];
      short8 o;
      #pragma unroll
      for (int j = 0; j < 4; ++j) { o[2*j] = (short)(cc[j] & 0xFFFF); o[2*j+1] = (short)(cc[j] >> 16); }
      *(short8*)(xb + (((size_t)(b*HP) + hp)*WP + wp)*ICN + icc*8) = o;
    }
  }
  if (chunk == 0 && tid < 8) {   // left border column wp=0
    short8 z = {0,0,0,0,0,0,0,0};
    *(short8*)(xb + (((size_t)(b*HP) + hp)*WP)*ICN + tid*8) = z;
  }
}

// ---------- prep_w: OIHW (bf16/fp32) -> [oc][tap*64+ic] bf16 ----------
__global__ __launch_bounds__(256) void prep_w(const void* __restrict__ wv_, u16* __restrict__ wb,
                                              const u32* __restrict__ xdet) {
  const bool isbf = detect_bf16(xdet);
  int o = blockIdx.x*256 + threadIdx.x;   // 0..73727
  int oc = o / 576;
  int k = o - oc*576;
  int tap = k >> 6;
  int ic = k & 63;
  int src = oc*576 + ic*9 + tap;
  wb[o] = isbf ? ((const u16*)wv_)[src] : f2bf(((const float*)wv_)[src]);
}

// ---------- fused conv3x3 + bias + min_oc + double tanh ----------
// A staged once in LDS (XOR-swizzled, conflict-free). B fragments loaded per-lane
// straight from global (wb is 147 KB -> L2-resident), register-prefetched one tap
// ahead. NO barriers in the tap loop.
__global__ __launch_bounds__(256, 3) void conv_min_kernel(
    const u16* __restrict__ xb, const u16* __restrict__ wb,
    const void* __restrict__ biasv, void* __restrict__ outv,
    const u32* __restrict__ xdet)
{
  __shared__ __align__(16) char ldsA[A_BYTES];   // 248 rows x 128 B
  float* minbuf = (float*)ldsA;                  // aliased post-loop (barrier-fenced)

  const int tid = threadIdx.x;
  const int wv = tid >> 6;
  const int lane = tid & 63;
  const int m15 = lane & 15;
  const int quad = lane >> 4;

  const bool isbf = detect_bf16(xdet);

  int bid = blockIdx.x;
  const int wsel = bid % 3;
  int rest = bid / 3;
  const int h = rest % HH;
  const int b = rest / HH;
  const int w0 = wsel * 72;                // 0,72,144

  // ---- stage A once: row r = dy*82 + wloc; 16B chunk c stored at slot c ^ (r&7).
  // q = tid+...: consecutive lanes -> consecutive 16B -> conflict-free writes.
  for (int q = tid; q < AROWS_USED*8; q += 256) {
    int r = q >> 3;
    int slot = q & 7;
    int c = slot ^ (r & 7);
    int dy = (r >= 164) ? 2 : ((r >= 82) ? 1 : 0);
    int wloc = r - dy*82;
    short8 v = *(const short8*)(xb + (((size_t)(b*HP + h + dy))*WP + (w0 + wloc))*ICN + c*8);
    *(short8*)(ldsA + r*128 + slot*16) = v;
  }

  // ---- per-lane B base: row oc = wv*32 + nb*16 + m15, k-chunk csel = ks*4 + quad
  const u16* bbase = wb + (wv*32 + m15)*576 + quad*8;
  short8 bcur[2][2], bnxt[2][2];
  #pragma unroll
  for (int nb = 0; nb < 2; ++nb)
    #pragma unroll
    for (int ks = 0; ks < 2; ++ks)
      bcur[nb][ks] = *(const short8*)(bbase + nb*16*576 + ks*32);

  floatx4 acc[5][2];
  #pragma unroll
  for (int mb = 0; mb < 5; ++mb) {
    acc[mb][0] = (floatx4){0.f,0.f,0.f,0.f};
    acc[mb][1] = (floatx4){0.f,0.f,0.f,0.f};
  }

  __syncthreads();                         // A visible to all waves

  for (int tap = 0; tap < 9; ++tap) {
    if (tap < 8) {                         // prefetch next tap's B frags (L2-hit)
      #pragma unroll
      for (int nb = 0; nb < 2; ++nb)
        #pragma unroll
        for (int ks = 0; ks < 2; ++ks)
          bnxt[nb][ks] = *(const short8*)(bbase + nb*16*576 + (tap+1)*64 + ks*32);
    }
    const int dy = tap / 3;
    const int dx = tap - dy*3;
    const int rbase = dy*82 + dx + m15;    // A row for this lane (+ mb*16)
    const char* ab = ldsA + rbase*128;
    #pragma unroll
    for (int ks = 0; ks < 2; ++ks) {
      const int csel = ks*4 + quad;
      const int aoff = (csel ^ (rbase & 7)) * 16;
      short8 af[5];
      #pragma unroll
      for (int mb = 0; mb < 5; ++mb)
        af[mb] = *(const short8*)(ab + mb*2048 + aoff);
      #pragma unroll
      for (int mb = 0; mb < 5; ++mb) {
        acc[mb][0] = __builtin_amdgcn_mfma_f32_16x16x32_bf16(af[mb], bcur[0][ks], acc[mb][0], 0, 0, 0);
        acc[mb][1] = __builtin_amdgcn_mfma_f32_16x16x32_bf16(af[mb], bcur[1][ks], acc[mb][1], 0, 0, 0);
      }
    }
    if (tap < 8) {
      #pragma unroll
      for (int nb = 0; nb < 2; ++nb)
        #pragma unroll
        for (int ks = 0; ks < 2; ++ks)
          bcur[nb][ks] = bnxt[nb][ks];
    }
  }
  __syncthreads();   // fence A reads before minbuf aliasing writes

  // ---- epilogue: +bias, min over oc, cross-lane/cross-wave min, tanh(tanh), store
  float bv0, bv1;
  if (isbf) {
    bv0 = __bfloat162float(((const __hip_bfloat16*)biasv)[wv*32 + m15]);
    bv1 = __bfloat162float(((const __hip_bfloat16*)biasv)[wv*32 + 16 + m15]);
  } else {
    bv0 = ((const float*)biasv)[wv*32 + m15];
    bv1 = ((const float*)biasv)[wv*32 + 16 + m15];
  }
  #pragma unroll
  for (int mb = 0; mb < 5; ++mb) {
    #pragma unroll
    for (int r = 0; r < 4; ++r) {
      float v = fminf(acc[mb][0][r] + bv0, acc[mb][1][r] + bv1);
      v = fminf(v, __shfl_xor(v, 1));
      v = fminf(v, __shfl_xor(v, 2));
      v = fminf(v, __shfl_xor(v, 4));
      v = fminf(v, __shfl_xor(v, 8));
      if (m15 == 0)
        minbuf[wv*MT + mb*16 + quad*4 + r] = v;   // pixel = mb*16 + quad*4 + r
    }
  }
  __syncthreads();
  if (tid < MT) {
    float v = fminf(fminf(minbuf[tid], minbuf[MT + tid]),
                    fminf(minbuf[2*MT + tid], minbuf[3*MT + tid]));
    float t = fast_tanh(fast_tanh(v));
    size_t oi = ((size_t)(b*HH + h))*WW + w0 + tid;
    if (isbf) ((__hip_bfloat16*)outv)[oi] = __float2bfloat16(t);
    else      ((float*)outv)[oi] = t;
  }
}

extern "C" void kernel_launch(void* const* d_in, const int* in_sizes, int n_in,
                              void* d_out, int out_size, void* d_ws, size_t ws_size,
                              hipStream_t stream) {
  (void)in_sizes; (void)n_in; (void)out_size;
  const size_t XB_BYTES = (size_t)BATCH*HP*WP*ICN*2;   // 104,603,648
  const size_t WB_BYTES = (size_t)OCN*ICN*9*2;         // 147,456
  if (ws_size < XB_BYTES + WB_BYTES) return;

  const void* x  = d_in[0];
  const void* w  = d_in[1];
  const void* bias = d_in[2];
  u16* xb = (u16*)d_ws;
  u16* wb = (u16*)((char*)d_ws + XB_BYTES);
  const u32* xdet = (const u32*)x;

  prep_x<<<BATCH*HP*4, 256, 0, stream>>>(x, xb);
  prep_w<<<288, 256, 0, stream>>>(w, wb, xdet);
  conv_min_kernel<<<3*HH*BATCH, 256, 0, stream>>>(xb, wb, bias, d_out, xdet);
}

// Round 5
// 488.199 us; speedup vs baseline: 1.2400x; 1.0178x over previous
//
#include <hip/hip_runtime.h>
#include <hip/hip_bf16.h>

typedef __attribute__((ext_vector_type(8))) short short8;
typedef __attribute__((ext_vector_type(4))) float floatx4;
typedef unsigned short u16;
typedef unsigned int u32;

#define BATCH 16
#define HH 224
#define WW 224
#define ICN 64
#define OCN 128
#define HP 226
#define WP 226

// conv tile: 2 output rows x 40 cols per WG (6 w-chunks; last overlaps, stores idempotent)
#define MT 80
#define AR 168            // 4 padded input rows x 42 padded cols
#define AQ (AR*8)         // 1344 16-B chunks
#define A_BYTES (AR*128)  // 21504

#define XB_BYTES ((size_t)BATCH*HP*WP*ICN*2)   // 104,603,648
#define WB_BYTES ((size_t)OCN*ICN*9*2)         // 147,456

__device__ __forceinline__ u16 f2bf(float f) {
  __hip_bfloat16 h = __float2bfloat16(f);
  return *reinterpret_cast<u16*>(&h);
}

__device__ __forceinline__ float fast_tanh(float x) {
  float e = __expf(2.0f * x);    // x>>0 -> 1, x<<0 -> -1, inf-safe
  return 1.0f - 2.0f / (e + 1.0f);
}

// ---------- detect_kernel: one wave decides container dtype, writes flag ----------
// bf16 containers: both u16 halves of every u32 have sane bf16 exponents (cnt=128).
// fp32 containers: low halves are mantissa bits, mostly out of range (cnt~80).
__global__ void detect_kernel(const u32* __restrict__ xw, u32* __restrict__ flag) {
  if (threadIdx.x == 0) {
    int cnt = 0;
    #pragma unroll 8
    for (int i = 0; i < 64; ++i) {
      u32 w = xw[i];
      int e0 = (w >> 7) & 0xFF;
      int e1 = (w >> 23) & 0xFF;
      cnt += (e0 >= 90 && e0 <= 160) ? 1 : 0;
      cnt += (e1 >= 90 && e1 <= 160) ? 1 : 0;
    }
    *flag = (cnt >= 120) ? 1u : 0u;
  }
}

// ---------- prep_x: NCHW (fp32 or bf16) -> zero-padded NHWC bf16 [b][226][226][64] ----------
// u32-granular LDS transpose (conflict-free both phases, verified R3); 2 rows/block.
__global__ __launch_bounds__(256) void prep_x(const void* __restrict__ xv, u16* __restrict__ xb,
                                              const u32* __restrict__ flag) {
  __shared__ u32 tile32[2][64*33];   // [w_local][ic_pair], stride 33
  const bool isbf = (*flag != 0u);
  const int tid = threadIdx.x;
  int bid = blockIdx.x;
  const int chunk = bid & 3;         // 4 chunks of 64 input cols
  int rest = bid >> 2;
  const int hp0 = rest % 113;        // rows hp0 and hp0+113
  const int b = rest / 113;
  const int wt = chunk * 64;
  const int icp = tid >> 3;          // ic pair 0..31
  const int oct = tid & 7;           // w octet 0..7
  const int w = wt + oct*8;
  const int ic0 = icp*2;

  #pragma unroll
  for (int t = 0; t < 2; ++t) {
    const int hp = hp0 + t*113;
    const int h = hp - 1;
    const bool valid = (h >= 0) && (h < HH) && (w < WW);
    const size_t b0 = (((size_t)(b*ICN + ic0))*HH + h)*WW + w;
    const size_t b1 = (((size_t)(b*ICN + ic0+1))*HH + h)*WW + w;
    u16 a[8], c[8];
    if (isbf) {
      short8 v0 = {0,0,0,0,0,0,0,0}, v1 = {0,0,0,0,0,0,0,0};
      if (valid) {
        v0 = *(const short8*)((const u16*)xv + b0);
        v1 = *(const short8*)((const u16*)xv + b1);
      }
      #pragma unroll
      for (int s = 0; s < 8; ++s) { a[s] = (u16)v0[s]; c[s] = (u16)v1[s]; }
    } else {
      floatx4 f0={0,0,0,0}, f1={0,0,0,0}, f2={0,0,0,0}, f3={0,0,0,0};
      if (valid) {
        const float* p0 = (const float*)xv + b0;
        const float* p1 = (const float*)xv + b1;
        f0 = *(const floatx4*)p0; f1 = *(const floatx4*)(p0+4);
        f2 = *(const floatx4*)p1; f3 = *(const floatx4*)(p1+4);
      }
      #pragma unroll
      for (int s = 0; s < 4; ++s) {
        a[s] = f2bf(f0[s]); a[4+s] = f2bf(f1[s]);
        c[s] = f2bf(f2[s]); c[4+s] = f2bf(f3[s]);
      }
    }
    #pragma unroll
    for (int s = 0; s < 8; ++s)
      tile32[t][(oct*8 + s)*33 + icp] = (u32)a[s] | ((u32)c[s] << 16);
  }
  __syncthreads();
  #pragma unroll
  for (int t = 0; t < 2; ++t) {
    const int hp = hp0 + t*113;
    #pragma unroll
    for (int p = 0; p < 2; ++p) {
      int idx = p*256 + tid;
      int wl = idx >> 3;
      int icc = idx & 7;
      int wp = wt + 1 + wl;
      if (wp < WP) {
        u32 cc[4];
        #pragma unroll
        for (int j = 0; j < 4; ++j) cc[j] = tile32[t][wl*33 + icc*4 + j];
        short8 o;
        #pragma unroll
        for (int j = 0; j < 4; ++j) { o[2*j] = (short)(cc[j] & 0xFFFF); o[2*j+1] = (short)(cc[j] >> 16); }
        *(short8*)(xb + (((size_t)(b*HP) + hp)*WP + wp)*ICN + icc*8) = o;
      }
    }
    if (chunk == 0 && tid < 8) {     // left border column wp=0
      short8 z = {0,0,0,0,0,0,0,0};
      *(short8*)(xb + (((size_t)(b*HP) + hp)*WP)*ICN + tid*8) = z;
    }
  }
}

// ---------- prep_w: OIHW (fp32 or bf16) -> [oc][tap*64+ic] bf16 ----------
__global__ __launch_bounds__(256) void prep_w(const void* __restrict__ wv_, u16* __restrict__ wb,
                                              const u32* __restrict__ flag) {
  const bool isbf = (*flag != 0u);
  int o = blockIdx.x*256 + threadIdx.x;   // 0..73727
  int oc = o / 576;
  int k = o - oc*576;
  int tap = k >> 6;
  int ic = k & 63;
  int src = oc*576 + ic*9 + tap;
  wb[o] = isbf ? ((const u16*)wv_)[src] : f2bf(((const float*)wv_)[src]);
}

// ---------- fused conv3x3 + bias + min_oc + double tanh ----------
// A staged once in LDS (XOR-swizzled, conflict-free). B per-lane from global
// (147 KB, L2-resident), register-prefetched. Tap loop fully unrolled, no
// barriers inside -> ds_read/MFMA pipelined across taps.
__global__ __launch_bounds__(256, 4) void conv_min_kernel(
    const u16* __restrict__ xb, const u16* __restrict__ wb,
    const void* __restrict__ biasv, void* __restrict__ outv,
    const u32* __restrict__ flag)
{
  __shared__ __align__(16) char ldsA[A_BYTES];   // 168 rows x 128 B
  float* minbuf = (float*)ldsA;                  // aliased post-loop (barrier-fenced)

  const bool isbf = (*flag != 0u);
  const int tid = threadIdx.x;
  const int wv = tid >> 6;
  const int lane = tid & 63;
  const int m15 = lane & 15;
  const int quad = lane >> 4;

  int bid = blockIdx.x;
  const int wsel = bid % 6;
  int rest = bid / 6;
  const int h0 = (rest % 112) * 2;
  const int b = rest / 112;
  const int w0 = (wsel < 5) ? wsel*40 : 184;     // last chunk overlaps; stores idempotent

  // ---- stage A once: row r = dyi*42 + wloc; chunk c at slot c ^ (r&7)
  for (int q = tid; q < AQ; q += 256) {
    int r = q >> 3;
    int slot = q & 7;
    int c = slot ^ (r & 7);
    int dyi = r / 42;
    int wloc = r - dyi*42;
    short8 v = *(const short8*)(xb + (((size_t)(b*HP + h0 + dyi))*WP + (w0 + wloc))*ICN + c*8);
    *(short8*)(ldsA + r*128 + slot*16) = v;
  }

  // ---- per-lane A-row bases: pixel p = mb*16 + m15 -> base = (p/40)*42 + p%40
  int arow[5];
  #pragma unroll
  for (int mb = 0; mb < 5; ++mb) {
    int p = mb*16 + m15;
    int ro = p / 40;
    arow[mb] = ro*42 + (p - ro*40);
  }

  // ---- per-lane B: row oc = wv*32 + nb*16 + m15, k-chunk = ks*4 + quad
  const u16* bbase = wb + (wv*32 + m15)*576 + quad*8;
  short8 bcur[2][2];
  #pragma unroll
  for (int nb = 0; nb < 2; ++nb)
    #pragma unroll
    for (int ks = 0; ks < 2; ++ks)
      bcur[nb][ks] = *(const short8*)(bbase + nb*16*576 + ks*32);

  floatx4 acc[5][2];
  #pragma unroll
  for (int mb = 0; mb < 5; ++mb) {
    acc[mb][0] = (floatx4){0.f,0.f,0.f,0.f};
    acc[mb][1] = (floatx4){0.f,0.f,0.f,0.f};
  }

  __syncthreads();                         // A visible to all waves

  #pragma unroll
  for (int tap = 0; tap < 9; ++tap) {
    short8 bnxt[2][2];
    if (tap < 8) {                         // prefetch next tap's B frags (L2-hit)
      #pragma unroll
      for (int nb = 0; nb < 2; ++nb)
        #pragma unroll
        for (int ks = 0; ks < 2; ++ks)
          bnxt[nb][ks] = *(const short8*)(bbase + nb*16*576 + (tap+1)*64 + ks*32);
    }
    const int dy = tap / 3;
    const int dx = tap - dy*3;
    const int rdelta = dy*42 + dx;
    #pragma unroll
    for (int ks = 0; ks < 2; ++ks) {
      const int csel = ks*4 + quad;
      short8 af[5];
      #pragma unroll
      for (int mb = 0; mb < 5; ++mb) {
        int row = arow[mb] + rdelta;
        af[mb] = *(const short8*)(ldsA + row*128 + ((csel ^ (row & 7))*16));
      }
      #pragma unroll
      for (int mb = 0; mb < 5; ++mb) {
        acc[mb][0] = __builtin_amdgcn_mfma_f32_16x16x32_bf16(af[mb], bcur[0][ks], acc[mb][0], 0, 0, 0);
        acc[mb][1] = __builtin_amdgcn_mfma_f32_16x16x32_bf16(af[mb], bcur[1][ks], acc[mb][1], 0, 0, 0);
      }
    }
    if (tap < 8) {
      #pragma unroll
      for (int nb = 0; nb < 2; ++nb)
        #pragma unroll
        for (int ks = 0; ks < 2; ++ks)
          bcur[nb][ks] = bnxt[nb][ks];
    }
  }
  __syncthreads();   // fence A reads before minbuf aliasing writes

  // ---- epilogue: +bias, min over oc, cross-lane/cross-wave min, tanh(tanh), store
  float bv0, bv1;
  if (isbf) {
    bv0 = __bfloat162float(((const __hip_bfloat16*)biasv)[wv*32 + m15]);
    bv1 = __bfloat162float(((const __hip_bfloat16*)biasv)[wv*32 + 16 + m15]);
  } else {
    bv0 = ((const float*)biasv)[wv*32 + m15];
    bv1 = ((const float*)biasv)[wv*32 + 16 + m15];
  }
  #pragma unroll
  for (int mb = 0; mb < 5; ++mb) {
    #pragma unroll
    for (int r = 0; r < 4; ++r) {
      float v = fminf(acc[mb][0][r] + bv0, acc[mb][1][r] + bv1);
      v = fminf(v, __shfl_xor(v, 1));
      v = fminf(v, __shfl_xor(v, 2));
      v = fminf(v, __shfl_xor(v, 4));
      v = fminf(v, __shfl_xor(v, 8));
      if (m15 == 0)
        minbuf[wv*MT + mb*16 + quad*4 + r] = v;   // pixel = mb*16 + quad*4 + r
    }
  }
  __syncthreads();
  if (tid < MT) {
    float v = fminf(fminf(minbuf[tid], minbuf[MT + tid]),
                    fminf(minbuf[2*MT + tid], minbuf[3*MT + tid]));
    float t = fast_tanh(fast_tanh(v));
    int ro = tid / 40;
    int co = tid - ro*40;
    size_t oi = ((size_t)(b*HH + h0 + ro))*WW + w0 + co;
    if (isbf) ((__hip_bfloat16*)outv)[oi] = __float2bfloat16(t);
    else      ((float*)outv)[oi] = t;
  }
}

extern "C" void kernel_launch(void* const* d_in, const int* in_sizes, int n_in,
                              void* d_out, int out_size, void* d_ws, size_t ws_size,
                              hipStream_t stream) {
  (void)in_sizes; (void)n_in; (void)out_size;
  if (ws_size < XB_BYTES + WB_BYTES + 16) return;

  const void* x  = d_in[0];
  const void* w  = d_in[1];
  const void* bias = d_in[2];
  u16* xb = (u16*)d_ws;
  u16* wb = (u16*)((char*)d_ws + XB_BYTES);
  u32* flag = (u32*)((char*)d_ws + XB_BYTES + WB_BYTES);

  detect_kernel<<<1, 64, 0, stream>>>((const u32*)x, flag);
  prep_x<<<BATCH*113*4, 256, 0, stream>>>(x, xb, flag);
  prep_w<<<288, 256, 0, stream>>>(w, wb, flag);
  conv_min_kernel<<<6*112*BATCH, 256, 0, stream>>>(xb, wb, bias, d_out, flag);
}